// Round 5
// baseline (215.726 us; speedup 1.0000x reference)
//
#include <hip/hip_runtime.h>
#include <hip/hip_bf16.h>
#include <stdint.h>
#include <stddef.h>

// DecorrLoss: grad = 0.5*mean_C(offdiag) + 0.5*diag(mean(x^2)-1), corr_loss, whit_loss
// x: f32 [8,4096,1024] -> [M=32768][D=1024]
//   pass1: f32 -> bf16 transposed XbT [D][M]; per-row sum(x^2), sum(x^4) partials
//   gemm : C = XbT*XbT^T, 36 upper-triangle 128x128 tiles, split-K, XCD-chunked.
//          ZERO-LDS: MFMA fragments loaded directly from global (L2-resident 2.7MB
//          chunk per XCD). No barriers, no waitcnt drain, no bank conflicts.
//   epi1 : reduce S partials -> csum[36][128][128]
//   epi2 : emit full grad (mirror lower), scale, diag fixup
//   fin1/fin2: deterministic scalar losses

#define D_DIM 1024
#define M_ROWS 32768
#define BK 32
#define NKB (M_ROWS / BK)          // 1024 K-blocks
#define NTILES 36                  // 8*9/2 triangle tiles
#define TILE_ELEMS 16384           // 128*128

typedef __attribute__((ext_vector_type(8))) short bf16x8;
typedef __attribute__((ext_vector_type(4))) float f32x4;

__device__ inline unsigned short f2bf(float f) {
  unsigned int b = __float_as_uint(f);
  return (unsigned short)((b + 0x7fffu + ((b >> 16) & 1u)) >> 16);  // RNE
}

// ---------------- pass 1: transpose+convert + row-stat partials ----------------
// grid: 512 m-tiles x 16 c-tiles = 8192 blocks, 256 threads
__global__ __launch_bounds__(256) void k_pass1(const float* __restrict__ x,
                                               unsigned short* __restrict__ xt,
                                               float* __restrict__ rssp,
                                               float* __restrict__ rs4p) {
  __shared__ unsigned short sh[64 * 76];  // 64 m x 64 c, stride 76 shorts
  const int bid = blockIdx.x;
  const int m0 = (bid & 511) * 64;
  const int ct = bid >> 9;            // c-tile 0..15
  const int c0 = ct * 64;
  const int t = (int)threadIdx.x;
  const int r16 = t >> 4, cg = t & 15;

#pragma unroll
  for (int mi = 0; mi < 4; ++mi) {
    const int m = mi * 16 + r16;
    const float4 v = *(const float4*)(x + (size_t)(m0 + m) * D_DIM + c0 + cg * 4);
    const float q0 = v.x * v.x, q1 = v.y * v.y, q2 = v.z * v.z, q3 = v.w * v.w;
    float ss = q0 + q1 + q2 + q3;
    float s4 = q0 * q0 + q1 * q1 + q2 * q2 + q3 * q3;
#pragma unroll
    for (int off = 8; off; off >>= 1) {
      ss += __shfl_xor(ss, off, 16);
      s4 += __shfl_xor(s4, off, 16);
    }
    if (cg == 0) {
      rssp[ct * M_ROWS + m0 + m] = ss;
      rs4p[ct * M_ROWS + m0 + m] = s4;
    }
    ushort4 pk;
    pk.x = f2bf(v.x); pk.y = f2bf(v.y); pk.z = f2bf(v.z); pk.w = f2bf(v.w);
    *(ushort4*)&sh[m * 76 + cg * 4] = pk;
  }
  __syncthreads();

#pragma unroll
  for (int ci = 0; ci < 2; ++ci) {
    const int c = ci * 32 + (t >> 3);
    const int ms = (t & 7) * 8;
    unsigned int w0 = sh[(ms + 0) * 76 + c] | ((unsigned int)sh[(ms + 1) * 76 + c] << 16);
    unsigned int w1 = sh[(ms + 2) * 76 + c] | ((unsigned int)sh[(ms + 3) * 76 + c] << 16);
    unsigned int w2 = sh[(ms + 4) * 76 + c] | ((unsigned int)sh[(ms + 5) * 76 + c] << 16);
    unsigned int w3 = sh[(ms + 6) * 76 + c] | ((unsigned int)sh[(ms + 7) * 76 + c] << 16);
    uint4 pk; pk.x = w0; pk.y = w1; pk.z = w2; pk.w = w3;
    *(uint4*)(xt + (size_t)(c0 + c) * M_ROWS + m0 + ms) = pk;
  }
}

// ---------------- gemm: zero-LDS direct-L2, upper-triangle, split-K, XCD-chunked ----
// grid: S * 36 blocks, 256 threads (4 waves, 2x2 of 64x64)
__global__ __launch_bounds__(256) void k_gemm(const unsigned short* __restrict__ xt,
                                              float* __restrict__ cpart, int S, int swz) {
  const int bid = (int)blockIdx.x;
  int s, tidx;
  if (swz) {
    const int xcd = bid & 7;
    tidx = (bid >> 3) % NTILES;
    s = (bid / (8 * NTILES)) * 8 + xcd;
  } else {
    s = bid / NTILES;
    tidx = bid - s * NTILES;
  }
  int rem = tidx, ti = 0;
  while (rem >= 8 - ti) { rem -= 8 - ti; ++ti; }
  const int tj = ti + rem;

  const int t = (int)threadIdx.x;
  const int l = t & 63, w = t >> 6;
  const int wr = w >> 1, wc = w & 1;
  const int r = l & 15, g = l >> 4;

  f32x4 acc[4][4];
#pragma unroll
  for (int m = 0; m < 4; ++m)
#pragma unroll
    for (int n = 0; n < 4; ++n) acc[m][n] = (f32x4){0.f, 0.f, 0.f, 0.f};

  // K partition: NKB blocks of BK over S splits
  const int q = NKB / S, rr = NKB - q * S;
  const int kb0 = s * q + (s < rr ? s : rr);
  const int nkb = q + (s < rr ? 1 : 0);
  const int kbeg = kb0 * BK;

  // Direct fragment pointers: lane (r,g) reads 16B of row (…*16+r) at k-col g*8.
  // Lanes {r, r+16, r+32, r+48} cover one contiguous 64B line of row r -> the
  // wave-instr touches 16 full lines (1KB), same L2 request stream as coalesced.
  const unsigned short* pa = xt + (size_t)(ti * 128 + wr * 64 + r) * M_ROWS + g * 8 + kbeg;
  const unsigned short* pb = xt + (size_t)(tj * 128 + wc * 64 + r) * M_ROWS + g * 8 + kbeg;
  const size_t RS = (size_t)16 * M_ROWS;  // 16-row stride (elems)

#pragma unroll 2
  for (int it = 0; it < nkb; ++it) {
    const bf16x8 a0 = *(const bf16x8*)(pa);
    const bf16x8 a1 = *(const bf16x8*)(pa + RS);
    const bf16x8 a2 = *(const bf16x8*)(pa + 2 * RS);
    const bf16x8 a3 = *(const bf16x8*)(pa + 3 * RS);
    const bf16x8 b0 = *(const bf16x8*)(pb);
    const bf16x8 b1 = *(const bf16x8*)(pb + RS);
    const bf16x8 b2 = *(const bf16x8*)(pb + 2 * RS);
    const bf16x8 b3 = *(const bf16x8*)(pb + 3 * RS);
    acc[0][0] = __builtin_amdgcn_mfma_f32_16x16x32_bf16(a0, b0, acc[0][0], 0, 0, 0);
    acc[0][1] = __builtin_amdgcn_mfma_f32_16x16x32_bf16(a0, b1, acc[0][1], 0, 0, 0);
    acc[0][2] = __builtin_amdgcn_mfma_f32_16x16x32_bf16(a0, b2, acc[0][2], 0, 0, 0);
    acc[0][3] = __builtin_amdgcn_mfma_f32_16x16x32_bf16(a0, b3, acc[0][3], 0, 0, 0);
    acc[1][0] = __builtin_amdgcn_mfma_f32_16x16x32_bf16(a1, b0, acc[1][0], 0, 0, 0);
    acc[1][1] = __builtin_amdgcn_mfma_f32_16x16x32_bf16(a1, b1, acc[1][1], 0, 0, 0);
    acc[1][2] = __builtin_amdgcn_mfma_f32_16x16x32_bf16(a1, b2, acc[1][2], 0, 0, 0);
    acc[1][3] = __builtin_amdgcn_mfma_f32_16x16x32_bf16(a1, b3, acc[1][3], 0, 0, 0);
    acc[2][0] = __builtin_amdgcn_mfma_f32_16x16x32_bf16(a2, b0, acc[2][0], 0, 0, 0);
    acc[2][1] = __builtin_amdgcn_mfma_f32_16x16x32_bf16(a2, b1, acc[2][1], 0, 0, 0);
    acc[2][2] = __builtin_amdgcn_mfma_f32_16x16x32_bf16(a2, b2, acc[2][2], 0, 0, 0);
    acc[2][3] = __builtin_amdgcn_mfma_f32_16x16x32_bf16(a2, b3, acc[2][3], 0, 0, 0);
    acc[3][0] = __builtin_amdgcn_mfma_f32_16x16x32_bf16(a3, b0, acc[3][0], 0, 0, 0);
    acc[3][1] = __builtin_amdgcn_mfma_f32_16x16x32_bf16(a3, b1, acc[3][1], 0, 0, 0);
    acc[3][2] = __builtin_amdgcn_mfma_f32_16x16x32_bf16(a3, b2, acc[3][2], 0, 0, 0);
    acc[3][3] = __builtin_amdgcn_mfma_f32_16x16x32_bf16(a3, b3, acc[3][3], 0, 0, 0);
    pa += BK; pb += BK;
  }

  // C/D layout: col = lane&15, row = (lane>>4)*4 + reg. Tile-local 128x128 write.
  float* cp = cpart + ((size_t)s * NTILES + tidx) * TILE_ELEMS;
#pragma unroll
  for (int m = 0; m < 4; ++m) {
    const int rowb = wr * 64 + m * 16 + g * 4;
#pragma unroll
    for (int n = 0; n < 4; ++n) {
      const int col = wc * 64 + n * 16 + r;
#pragma unroll
      for (int qq = 0; qq < 4; ++qq)
        cp[(size_t)(rowb + qq) * 128 + col] = acc[m][n][qq];
    }
  }
}

// ---------------- epi1: reduce S partials -> csum ----------------
__global__ __launch_bounds__(256) void k_epi1(const float* __restrict__ cpart,
                                              float* __restrict__ csum, int S) {
  const int g4 = ((int)blockIdx.x * 256 + (int)threadIdx.x) * 4;
  f32x4 a = (f32x4){0.f, 0.f, 0.f, 0.f};
  for (int s = 0; s < S; ++s) {
    const f32x4 v = *(const f32x4*)(cpart + (size_t)s * (NTILES * TILE_ELEMS) + g4);
    a += v;
  }
  *(f32x4*)(csum + g4) = a;
}

// ---------------- epi2: emit full grad, mirror lower, diag fixup ----------------
__global__ __launch_bounds__(256) void k_epi2(const float* __restrict__ csum,
                                              float* __restrict__ out) {
  const int idx = (int)blockIdx.x * 256 + (int)threadIdx.x;  // 0..262143
  const int i = idx >> 8;
  const int j0 = (idx & 255) * 4;
  const int ti = i >> 7, tj = j0 >> 7;
  const float sc = 0.5f / (float)M_ROWS;
  float4 o;
  if (ti <= tj) {
    const int src = ti * 8 - (ti * (ti - 1)) / 2 + tj - ti;
    const float4 v = *(const float4*)(csum + (size_t)src * TILE_ELEMS +
                                      (size_t)(i & 127) * 128 + (j0 & 127));
    o.x = v.x * sc; o.y = v.y * sc; o.z = v.z * sc; o.w = v.w * sc;
    if (i >= j0 && i < j0 + 4) {
      const float cd = (i == j0) ? v.x : (i == j0 + 1) ? v.y : (i == j0 + 2) ? v.z : v.w;
      const float dv = 0.5f * (cd / (float)M_ROWS - 1.0f);
      if (i == j0) o.x = dv; else if (i == j0 + 1) o.y = dv;
      else if (i == j0 + 2) o.z = dv; else o.w = dv;
    }
  } else {
    const int src = tj * 8 - (tj * (tj - 1)) / 2 + ti - tj;
    const int jj = j0 & 127, ii = i & 127;
    const float* base = csum + (size_t)src * TILE_ELEMS + ii;
    o.x = base[(size_t)(jj + 0) * 128] * sc;
    o.y = base[(size_t)(jj + 1) * 128] * sc;
    o.z = base[(size_t)(jj + 2) * 128] * sc;
    o.w = base[(size_t)(jj + 3) * 128] * sc;
  }
  *(float4*)(out + (size_t)i * D_DIM + j0) = o;
}

// ---------------- fin1: row stats reduce over 16 c-tiles + block partials ----------------
__global__ __launch_bounds__(256) void k_fin1(const float* __restrict__ rssp,
                                              const float* __restrict__ rs4p,
                                              float* __restrict__ scp) {
  __shared__ float sm[3][4];
  const int t = (int)threadIdx.x;
  const int m = (int)blockIdx.x * 256 + t;
  float a = 0.f, b = 0.f;
#pragma unroll
  for (int ct = 0; ct < 16; ++ct) {
    a += rssp[ct * M_ROWS + m];
    b += rs4p[ct * M_ROWS + m];
  }
  float corr = a * a - b;
#pragma unroll
  for (int off = 32; off; off >>= 1) {
    corr += __shfl_down(corr, off);
    a += __shfl_down(a, off);
    b += __shfl_down(b, off);
  }
  const int wv = t >> 6;
  if ((t & 63) == 0) { sm[0][wv] = corr; sm[1][wv] = a; sm[2][wv] = b; }
  __syncthreads();
  if (t == 0) {
    float c4 = 0.f, a4 = 0.f, b4 = 0.f;
#pragma unroll
    for (int i = 0; i < 4; ++i) { c4 += sm[0][i]; a4 += sm[1][i]; b4 += sm[2][i]; }
    scp[(int)blockIdx.x * 4 + 0] = c4;
    scp[(int)blockIdx.x * 4 + 1] = a4;
    scp[(int)blockIdx.x * 4 + 2] = b4;
  }
}

// ---------------- fin2: final scalars ----------------
__global__ __launch_bounds__(128) void k_fin2(const float* __restrict__ scp,
                                              float* __restrict__ out) {
  __shared__ float sm[3][2];
  const int t = (int)threadIdx.x;  // 0..127
  float c = scp[t * 4 + 0], a = scp[t * 4 + 1], b = scp[t * 4 + 2];
#pragma unroll
  for (int off = 32; off; off >>= 1) {
    c += __shfl_down(c, off);
    a += __shfl_down(a, off);
    b += __shfl_down(b, off);
  }
  const int wv = t >> 6;
  if ((t & 63) == 0) { sm[0][wv] = c; sm[1][wv] = a; sm[2][wv] = b; }
  __syncthreads();
  if (t == 0) {
    const double ct = (double)sm[0][0] + (double)sm[0][1];
    const double st = (double)sm[1][0] + (double)sm[1][1];
    const double qt = (double)sm[2][0] + (double)sm[2][1];
    const double N = (double)M_ROWS * (double)D_DIM;
    out[1048576] = (float)(ct / (double)M_ROWS / ((double)D_DIM * (double)D_DIM));
    out[1048577] = (float)((qt - 2.0 * st + N) / N);
  }
}

extern "C" void kernel_launch(void* const* d_in, const int* in_sizes, int n_in,
                              void* d_out, int out_size, void* d_ws, size_t ws_size,
                              hipStream_t stream) {
  (void)in_sizes; (void)n_in; (void)out_size;
  const float* x = (const float*)d_in[0];
  float* out = (float*)d_out;
  char* ws = (char*)d_ws;

  // ws layout:
  unsigned short* xt = (unsigned short*)ws;                 // 67,108,864 B
  float* rssp = (float*)(ws + 67108864);                    //  2,097,152 B
  float* rs4p = (float*)(ws + 69206016);                    //  2,097,152 B
  float* scp  = (float*)(ws + 71303168);                    //      4,096 B
  float* csum = (float*)(ws + 71307264);                    //  2,359,296 B
  float* cpart = (float*)(ws + 73666560);                   //  S * 2,359,296 B
  const size_t base = 73666560;
  size_t avail = (ws_size > base) ? (ws_size - base) : 0;
  int S = (int)(avail / (sizeof(float) * NTILES * TILE_ELEMS));
  if (S > 24) S = 24;                 // 24 splits: 864 blocks, 2.7MB L2 chunk/XCD
  int swz = 0;
  if (S >= 8) { S &= ~7; swz = 1; }   // multiple of 8 -> XCD-chunked decode
  if (S < 1) S = 1;

  k_pass1<<<8192, 256, 0, stream>>>(x, xt, rssp, rs4p);
  k_gemm<<<NTILES * S, 256, 0, stream>>>(xt, cpart, S, swz);
  k_epi1<<<576, 256, 0, stream>>>(cpart, csum, S);
  k_epi2<<<1024, 256, 0, stream>>>(csum, out);
  k_fin1<<<128, 256, 0, stream>>>(rssp, rs4p, scp);
  k_fin2<<<1, 128, 0, stream>>>(scp, out);
}

// Round 6
// 104.521 us; speedup vs baseline: 2.0640x; 2.0640x over previous
//
#include <hip/hip_runtime.h>
#include <hip/hip_bf16.h>
#include <stdint.h>
#include <stddef.h>

// DecorrLoss: grad = 0.5*mean_C(offdiag) + 0.5*diag(mean(x^2)-1), corr_loss, whit_loss
// x: f32 [8,4096,1024] -> [M=32768][D=1024]
//   pass1: f32 -> fp8 e4m3 transposed XT [D][M]; per-row sum(x^2), sum(x^4) partials
//   gemm : C = XT*XT^T (fp8 MFMA 16x16x32), 36 upper-triangle 128x128 tiles,
//          split-K S=24, XCD-chunked, BK=64, 2-phase double-buffered LDS,
//          16B XOR swizzle via pre-swizzled global source (linear LDS dest).
//   epi1 : reduce S partials -> csum[36][128][128]
//   epi2 : emit full grad (mirror lower), scale, diag fixup
//   fin1/fin2: deterministic scalar losses (f32 path, unaffected by fp8)

#define D_DIM 1024
#define M_ROWS 32768
#define BK 64
#define NKB64 (M_ROWS / BK)        // 512 K-blocks of 64
#define NTILES 36                  // 8*9/2 triangle tiles
#define TILE_ELEMS 16384           // 128*128

typedef __attribute__((ext_vector_type(4))) float f32x4;

// RNE float -> OCP e4m3fn (bias 7, max 448, subnormal quantum 2^-9)
__device__ inline unsigned int f2e4m3(float f) {
  unsigned int u = __float_as_uint(f);
  unsigned int s = (u >> 24) & 0x80u;
  unsigned int a = u & 0x7FFFFFFFu;
  unsigned int m20 = a + 0x0007FFFFu + ((a >> 20) & 1u);  // RNE drop 20 bits
  unsigned int nrm = (m20 >> 20) - 960u;                  // (exp-120)<<3 | mant
  float af = __uint_as_float(a);
  unsigned int sub = (unsigned int)__float2int_rn(af * 512.0f);
  unsigned int mag = (a < 0x3C800000u) ? sub : nrm;       // < 2^-6 -> subnormal
  mag = (a >= 0x43E00000u) ? 0x7Eu : mag;                 // >= 448 -> clamp
  return s | mag;
}

__device__ inline void gload_lds16(const void* g, void* l) {
  __builtin_amdgcn_global_load_lds(
      (const __attribute__((address_space(1))) void*)g,
      (__attribute__((address_space(3))) void*)l,
      16, 0, 0);
}

// ---------------- pass 1: transpose + f32->fp8 + row-stat partials ----------------
// grid: 512 m-tiles x 16 c-tiles = 8192 blocks, 256 threads
__global__ __launch_bounds__(256) void k_pass1(const float* __restrict__ x,
                                               unsigned char* __restrict__ xt,
                                               float* __restrict__ rssp,
                                               float* __restrict__ rs4p) {
  __shared__ unsigned char sh[64 * 68];  // 64 m x 64 c fp8, stride 68
  const int bid = blockIdx.x;
  const int m0 = (bid & 511) * 64;
  const int ct = bid >> 9;            // c-tile 0..15
  const int c0 = ct * 64;
  const int t = (int)threadIdx.x;
  const int r16 = t >> 4, cg = t & 15;

#pragma unroll
  for (int mi = 0; mi < 4; ++mi) {
    const int m = mi * 16 + r16;
    const float4 v = *(const float4*)(x + (size_t)(m0 + m) * D_DIM + c0 + cg * 4);
    const float q0 = v.x * v.x, q1 = v.y * v.y, q2 = v.z * v.z, q3 = v.w * v.w;
    float ss = q0 + q1 + q2 + q3;
    float s4 = q0 * q0 + q1 * q1 + q2 * q2 + q3 * q3;
#pragma unroll
    for (int off = 8; off; off >>= 1) {
      ss += __shfl_xor(ss, off, 16);
      s4 += __shfl_xor(s4, off, 16);
    }
    if (cg == 0) {
      rssp[ct * M_ROWS + m0 + m] = ss;
      rs4p[ct * M_ROWS + m0 + m] = s4;
    }
    const unsigned int w = f2e4m3(v.x) | (f2e4m3(v.y) << 8) |
                           (f2e4m3(v.z) << 16) | (f2e4m3(v.w) << 24);
    *(unsigned int*)&sh[m * 68 + cg * 4] = w;
  }
  __syncthreads();

  // write phase: thread t -> column c = t&63, m-chunk mc = t>>6 (16 bytes)
  const int c = t & 63, mc = t >> 6;
  unsigned int ww[4];
#pragma unroll
  for (int qd = 0; qd < 4; ++qd) {
    const int mb = mc * 16 + qd * 4;
    ww[qd] = (unsigned int)sh[(mb + 0) * 68 + c] |
             ((unsigned int)sh[(mb + 1) * 68 + c] << 8) |
             ((unsigned int)sh[(mb + 2) * 68 + c] << 16) |
             ((unsigned int)sh[(mb + 3) * 68 + c] << 24);
  }
  uint4 pk; pk.x = ww[0]; pk.y = ww[1]; pk.z = ww[2]; pk.w = ww[3];
  *(uint4*)(xt + ((size_t)(c0 + c) << 15) + m0 + mc * 16) = pk;
}

// ---------------- gemm: fp8, BK=64, 2-phase dbuf, triangle, split-K, XCD-chunked ----
// grid: S * 36 blocks, 256 threads (4 waves, 2x2 of 64x64)
__global__ __launch_bounds__(256) void k_gemm(const unsigned char* __restrict__ xt,
                                              float* __restrict__ cpart, int S, int swz) {
  __shared__ unsigned char As[2][8192];
  __shared__ unsigned char Bs[2][8192];
  const int bid = (int)blockIdx.x;
  int s, tidx;
  if (swz) {
    const int xcd = bid & 7;
    tidx = (bid >> 3) % NTILES;
    s = (bid / (8 * NTILES)) * 8 + xcd;
  } else {
    s = bid / NTILES;
    tidx = bid - s * NTILES;
  }
  int rem = tidx, ti = 0;
  while (rem >= 8 - ti) { rem -= 8 - ti; ++ti; }
  const int tj = ti + rem;
  const bool diag = (ti == tj);

  const int t = (int)threadIdx.x;
  const int l = t & 63, w = t >> 6;
  const int wr = w >> 1, wc = w & 1;
  const int r = l & 15, g = l >> 4;

  f32x4 acc[4][4];
#pragma unroll
  for (int mi = 0; mi < 4; ++mi)
#pragma unroll
    for (int ni = 0; ni < 4; ++ni) acc[mi][ni] = (f32x4){0.f, 0.f, 0.f, 0.f};

  // staging: thread t covers LDS bytes [i*4096 + t*16, +16), i=0,1 per matrix.
  // LDS linear layout: row*64 + kbyte, row = i*64 + (t>>2).
  // Pre-swizzled GLOBAL source: fetch k-chunk (t&3)*16 ^ ((row&3)<<4) so the
  // swizzled ds_read below sees logical k. (16B-granular XOR keeps contiguity.)
  const int srow = t >> 2;
  const int skb = ((t & 3) * 16) ^ ((srow & 3) << 4);
  const unsigned char* pa0 = xt + ((size_t)(ti * 128 + srow) << 15) + skb;
  const unsigned char* pa1 = pa0 + ((size_t)64 << 15);
  const unsigned char* pb0 = xt + ((size_t)(tj * 128 + srow) << 15) + skb;
  const unsigned char* pb1 = pb0 + ((size_t)64 << 15);

#define STAGE(B, K) do { \
    gload_lds16(pa0 + (K), &As[B][t * 16]); \
    gload_lds16(pa1 + (K), &As[B][4096 + t * 16]); \
    if (!diag) { \
      gload_lds16(pb0 + (K), &Bs[B][t * 16]); \
      gload_lds16(pb1 + (K), &Bs[B][4096 + t * 16]); \
    } \
  } while (0)

  // fragment read offsets (swizzled): lane (r,g) of frag mi reads 8B at
  // row = base + mi*16 + r, kbyte = (kk*32 + g*8) ^ ((r&3)<<4)
  const int sw = (r & 3) << 4;
  const int o0 = (g * 8) ^ sw;
  const int o1 = (32 + g * 8) ^ sw;
  const int arow = (wr * 64 + r) * 64;
  const int brow = (wc * 64 + r) * 64;

#define COMPUTE(B, DS, SB, KN) do { \
    long long av[4][2], bv[4][2]; \
    const unsigned char* Ab = As[B]; \
    const unsigned char* Bb = diag ? As[B] : Bs[B]; \
    _Pragma("unroll") \
    for (int mi = 0; mi < 4; ++mi) { \
      av[mi][0] = *(const long long*)(Ab + arow + mi * 1024 + o0); \
      av[mi][1] = *(const long long*)(Ab + arow + mi * 1024 + o1); \
      bv[mi][0] = *(const long long*)(Bb + brow + mi * 1024 + o0); \
      bv[mi][1] = *(const long long*)(Bb + brow + mi * 1024 + o1); \
    } \
    if (DS) STAGE(SB, KN); \
    _Pragma("unroll") \
    for (int mi = 0; mi < 4; ++mi) \
      _Pragma("unroll") \
      for (int ni = 0; ni < 4; ++ni) { \
        acc[mi][ni] = __builtin_amdgcn_mfma_f32_16x16x32_fp8_fp8( \
            av[mi][0], bv[ni][0], acc[mi][ni], 0, 0, 0); \
        acc[mi][ni] = __builtin_amdgcn_mfma_f32_16x16x32_fp8_fp8( \
            av[mi][1], bv[ni][1], acc[mi][ni], 0, 0, 0); \
      } \
    __syncthreads(); \
  } while (0)

  // K partition: NKB64 blocks of 64 over S splits
  const int kq = NKB64 / S, kr = NKB64 - kq * S;
  const int kb0 = s * kq + (s < kr ? s : kr);
  const int nkb = kq + (s < kr ? 1 : 0);
  size_t k = (size_t)kb0 * BK;

  STAGE(0, k);
  __syncthreads();
  int it = 0;
  for (; it + 2 <= nkb; it += 2) {
    COMPUTE(0, 1, 1, k + 64);                    // read buf0, stage buf1
    COMPUTE(1, (it + 2 < nkb), 0, k + 128);      // read buf1, stage buf0
    k += 128;
  }
  if (it < nkb) COMPUTE(0, 0, 0, 0);             // odd tail, no stage

#undef STAGE
#undef COMPUTE

  // C/D layout: col = lane&15, row = (lane>>4)*4 + reg. Tile-local 128x128 write.
  float* cp = cpart + ((size_t)s * NTILES + tidx) * TILE_ELEMS;
#pragma unroll
  for (int mi = 0; mi < 4; ++mi) {
    const int rowb = wr * 64 + mi * 16 + g * 4;
#pragma unroll
    for (int ni = 0; ni < 4; ++ni) {
      const int col = wc * 64 + ni * 16 + r;
#pragma unroll
      for (int qq = 0; qq < 4; ++qq)
        cp[(size_t)(rowb + qq) * 128 + col] = acc[mi][ni][qq];
    }
  }
}

// ---------------- epi1: reduce S partials -> csum ----------------
__global__ __launch_bounds__(256) void k_epi1(const float* __restrict__ cpart,
                                              float* __restrict__ csum, int S) {
  const int g4 = ((int)blockIdx.x * 256 + (int)threadIdx.x) * 4;
  f32x4 a = (f32x4){0.f, 0.f, 0.f, 0.f};
  for (int s = 0; s < S; ++s) {
    const f32x4 v = *(const f32x4*)(cpart + (size_t)s * (NTILES * TILE_ELEMS) + g4);
    a += v;
  }
  *(f32x4*)(csum + g4) = a;
}

// ---------------- epi2: emit full grad, mirror lower, diag fixup ----------------
__global__ __launch_bounds__(256) void k_epi2(const float* __restrict__ csum,
                                              float* __restrict__ out) {
  const int idx = (int)blockIdx.x * 256 + (int)threadIdx.x;  // 0..262143
  const int i = idx >> 8;
  const int j0 = (idx & 255) * 4;
  const int ti = i >> 7, tj = j0 >> 7;
  const float sc = 0.5f / (float)M_ROWS;
  float4 o;
  if (ti <= tj) {
    const int src = ti * 8 - (ti * (ti - 1)) / 2 + tj - ti;
    const float4 v = *(const float4*)(csum + (size_t)src * TILE_ELEMS +
                                      (size_t)(i & 127) * 128 + (j0 & 127));
    o.x = v.x * sc; o.y = v.y * sc; o.z = v.z * sc; o.w = v.w * sc;
    if (i >= j0 && i < j0 + 4) {
      const float cd = (i == j0) ? v.x : (i == j0 + 1) ? v.y : (i == j0 + 2) ? v.z : v.w;
      const float dv = 0.5f * (cd / (float)M_ROWS - 1.0f);
      if (i == j0) o.x = dv; else if (i == j0 + 1) o.y = dv;
      else if (i == j0 + 2) o.z = dv; else o.w = dv;
    }
  } else {
    const int src = tj * 8 - (tj * (tj - 1)) / 2 + ti - tj;
    const int jj = j0 & 127, ii = i & 127;
    const float* base = csum + (size_t)src * TILE_ELEMS + ii;
    o.x = base[(size_t)(jj + 0) * 128] * sc;
    o.y = base[(size_t)(jj + 1) * 128] * sc;
    o.z = base[(size_t)(jj + 2) * 128] * sc;
    o.w = base[(size_t)(jj + 3) * 128] * sc;
  }
  *(float4*)(out + (size_t)i * D_DIM + j0) = o;
}

// ---------------- fin1: row stats reduce over 16 c-tiles + block partials ----------------
__global__ __launch_bounds__(256) void k_fin1(const float* __restrict__ rssp,
                                              const float* __restrict__ rs4p,
                                              float* __restrict__ scp) {
  __shared__ float sm[3][4];
  const int t = (int)threadIdx.x;
  const int m = (int)blockIdx.x * 256 + t;
  float a = 0.f, b = 0.f;
#pragma unroll
  for (int ct = 0; ct < 16; ++ct) {
    a += rssp[ct * M_ROWS + m];
    b += rs4p[ct * M_ROWS + m];
  }
  float corr = a * a - b;
#pragma unroll
  for (int off = 32; off; off >>= 1) {
    corr += __shfl_down(corr, off);
    a += __shfl_down(a, off);
    b += __shfl_down(b, off);
  }
  const int wv = t >> 6;
  if ((t & 63) == 0) { sm[0][wv] = corr; sm[1][wv] = a; sm[2][wv] = b; }
  __syncthreads();
  if (t == 0) {
    float c4 = 0.f, a4 = 0.f, b4 = 0.f;
#pragma unroll
    for (int i = 0; i < 4; ++i) { c4 += sm[0][i]; a4 += sm[1][i]; b4 += sm[2][i]; }
    scp[(int)blockIdx.x * 4 + 0] = c4;
    scp[(int)blockIdx.x * 4 + 1] = a4;
    scp[(int)blockIdx.x * 4 + 2] = b4;
  }
}

// ---------------- fin2: final scalars ----------------
__global__ __launch_bounds__(128) void k_fin2(const float* __restrict__ scp,
                                              float* __restrict__ out) {
  __shared__ float sm[3][2];
  const int t = (int)threadIdx.x;  // 0..127
  float c = scp[t * 4 + 0], a = scp[t * 4 + 1], b = scp[t * 4 + 2];
#pragma unroll
  for (int off = 32; off; off >>= 1) {
    c += __shfl_down(c, off);
    a += __shfl_down(a, off);
    b += __shfl_down(b, off);
  }
  const int wv = t >> 6;
  if ((t & 63) == 0) { sm[0][wv] = c; sm[1][wv] = a; sm[2][wv] = b; }
  __syncthreads();
  if (t == 0) {
    const double ct = (double)sm[0][0] + (double)sm[0][1];
    const double st = (double)sm[1][0] + (double)sm[1][1];
    const double qt = (double)sm[2][0] + (double)sm[2][1];
    const double N = (double)M_ROWS * (double)D_DIM;
    out[1048576] = (float)(ct / (double)M_ROWS / ((double)D_DIM * (double)D_DIM));
    out[1048577] = (float)((qt - 2.0 * st + N) / N);
  }
}

extern "C" void kernel_launch(void* const* d_in, const int* in_sizes, int n_in,
                              void* d_out, int out_size, void* d_ws, size_t ws_size,
                              hipStream_t stream) {
  (void)in_sizes; (void)n_in; (void)out_size;
  const float* x = (const float*)d_in[0];
  float* out = (float*)d_out;
  char* ws = (char*)d_ws;

  // ws layout:
  unsigned char* xt = (unsigned char*)ws;                   // 33,554,432 B (fp8)
  float* rssp = (float*)(ws + 33554432);                    //  2,097,152 B
  float* rs4p = (float*)(ws + 35651584);                    //  2,097,152 B
  float* scp  = (float*)(ws + 37748736);                    //      4,096 B
  float* csum = (float*)(ws + 37752832);                    //  2,359,296 B
  float* cpart = (float*)(ws + 40112128);                   //  S * 2,359,296 B
  const size_t base = 40112128;
  size_t avail = (ws_size > base) ? (ws_size - base) : 0;
  int S = (int)(avail / (sizeof(float) * NTILES * TILE_ELEMS));
  if (S > 24) S = 24;                 // 24 splits: 864 blocks, ~1.4MB L2 chunk/XCD
  int swz = 0;
  if (S >= 8) { S &= ~7; swz = 1; }   // multiple of 8 -> XCD-chunked decode
  if (S < 1) S = 1;

  k_pass1<<<8192, 256, 0, stream>>>(x, xt, rssp, rs4p);
  k_gemm<<<NTILES * S, 256, 0, stream>>>(xt, cpart, S, swz);
  k_epi1<<<576, 256, 0, stream>>>(cpart, csum, S);
  k_epi2<<<1024, 256, 0, stream>>>(csum, out);
  k_fin1<<<128, 256, 0, stream>>>(rssp, rs4p, scp);
  k_fin2<<<1, 128, 0, stream>>>(scp, out);
}

// Round 7
// 101.471 us; speedup vs baseline: 2.1260x; 1.0301x over previous
//
#include <hip/hip_runtime.h>
#include <hip/hip_bf16.h>
#include <stdint.h>
#include <stddef.h>

// DecorrLoss: grad = 0.5*mean_C(offdiag) + 0.5*diag(mean(x^2)-1), corr_loss, whit_loss
// x: f32 [8,4096,1024] -> [M=32768][D=1024]
//   pass1: f32 -> fp8 e4m3 (HW cvt_pk) transposed XT [D][M]; 4x4 register byte-
//          transpose via v_perm_b32; per-row sum(x^2), sum(x^4) partials
//   gemm : C = XT*XT^T (fp8 MFMA 16x16x32), 36 upper-triangle 128x128 tiles,
//          split-K S=24, XCD-chunked, BK=64, 2-phase double-buffered LDS,
//          16B XOR swizzle via pre-swizzled global source (linear LDS dest).
//   epi1 : reduce S partials -> csum[36][128][128]
//   epi2 : emit full grad (mirror lower), scale, diag fixup
//   fin1/fin2: deterministic scalar losses (f32 path, unaffected by fp8)

#define D_DIM 1024
#define M_ROWS 32768
#define BK 64
#define NKB64 (M_ROWS / BK)        // 512 K-blocks of 64
#define NTILES 36                  // 8*9/2 triangle tiles
#define TILE_ELEMS 16384           // 128*128

typedef __attribute__((ext_vector_type(4))) float f32x4;

__device__ inline void gload_lds16(const void* g, void* l) {
  __builtin_amdgcn_global_load_lds(
      (const __attribute__((address_space(1))) void*)g,
      (__attribute__((address_space(3))) void*)l,
      16, 0, 0);
}

// ---------------- pass 1: transpose + f32->fp8 (HW) + row-stat partials ----------------
// grid: 512 m-tiles x 16 c-tiles = 8192 blocks, 256 threads
// thread (q = t>>4, cg = t&15): rows m0+4q..+3, cols c0+4cg..+3
__global__ __launch_bounds__(256) void k_pass1(const float* __restrict__ x,
                                               unsigned char* __restrict__ xt,
                                               float* __restrict__ rssp,
                                               float* __restrict__ rs4p) {
  __shared__ unsigned int sh32[16 * 68];  // [m-group 0..15][64 cols + 4 pad] u32
  const int bid = blockIdx.x;
  const int m0 = (bid & 511) * 64;
  const int ct = bid >> 9;            // c-tile 0..15
  const int c0 = ct * 64;
  const int t = (int)threadIdx.x;
  const int q = t >> 4;               // m-group (4 rows)
  const int cg = t & 15;              // col group (4 cols)

  unsigned int p[4];
  float ss[4], s4[4];
#pragma unroll
  for (int mi = 0; mi < 4; ++mi) {
    const float4 v = *(const float4*)(x + (size_t)(m0 + q * 4 + mi) * D_DIM + c0 + cg * 4);
    const float q0 = v.x * v.x, q1 = v.y * v.y, q2 = v.z * v.z, q3 = v.w * v.w;
    ss[mi] = q0 + q1 + q2 + q3;
    s4[mi] = q0 * q0 + q1 * q1 + q2 * q2 + q3 * q3;
    unsigned int u = (unsigned int)__builtin_amdgcn_cvt_pk_fp8_f32(v.x, v.y, 0, false);
    p[mi] = (unsigned int)__builtin_amdgcn_cvt_pk_fp8_f32(v.z, v.w, (int)u, true);
  }
  // reduce stats across the 16 cg lanes (q constant within each 16-lane group)
#pragma unroll
  for (int off = 8; off; off >>= 1) {
#pragma unroll
    for (int mi = 0; mi < 4; ++mi) {
      ss[mi] += __shfl_xor(ss[mi], off, 16);
      s4[mi] += __shfl_xor(s4[mi], off, 16);
    }
  }
  if (cg == 0) {
#pragma unroll
    for (int mi = 0; mi < 4; ++mi) {
      rssp[ct * M_ROWS + m0 + q * 4 + mi] = ss[mi];
      rs4p[ct * M_ROWS + m0 + q * 4 + mi] = s4[mi];
    }
  }

  // 4x4 byte transpose in registers: w[c] = {p0.b[c], p1.b[c], p2.b[c], p3.b[c]}
  // v_perm_b32(a,b,sel): sel byte 0-3 -> b.byte, 4-7 -> a.byte
  const unsigned int t01l = __builtin_amdgcn_perm(p[1], p[0], 0x05010400u);
  const unsigned int t01h = __builtin_amdgcn_perm(p[1], p[0], 0x07030602u);
  const unsigned int t23l = __builtin_amdgcn_perm(p[3], p[2], 0x05010400u);
  const unsigned int t23h = __builtin_amdgcn_perm(p[3], p[2], 0x07030602u);
  uint4 w;
  w.x = __builtin_amdgcn_perm(t23l, t01l, 0x05040100u);  // col 4cg+0, rows 4q..4q+3
  w.y = __builtin_amdgcn_perm(t23l, t01l, 0x07060302u);  // col 4cg+1
  w.z = __builtin_amdgcn_perm(t23h, t01h, 0x05040100u);  // col 4cg+2
  w.w = __builtin_amdgcn_perm(t23h, t01h, 0x07060302u);  // col 4cg+3
  *(uint4*)&sh32[q * 68 + cg * 4] = w;   // byte addr q*272 + cg*16, 16B aligned
  __syncthreads();

  // write-out: lane -> (row c of xt, 16B m-chunk mh); wave covers 16 full 64B lines
  const int c = t >> 2, mh = t & 3;
  uint4 o;
  o.x = sh32[(mh * 4 + 0) * 68 + c];
  o.y = sh32[(mh * 4 + 1) * 68 + c];
  o.z = sh32[(mh * 4 + 2) * 68 + c];
  o.w = sh32[(mh * 4 + 3) * 68 + c];
  *(uint4*)(xt + ((size_t)(c0 + c) << 15) + m0 + mh * 16) = o;
}

// ---------------- gemm: fp8, BK=64, 2-phase dbuf, triangle, split-K, XCD-chunked ----
// grid: S * 36 blocks, 256 threads (4 waves, 2x2 of 64x64)
__global__ __launch_bounds__(256) void k_gemm(const unsigned char* __restrict__ xt,
                                              float* __restrict__ cpart, int S, int swz) {
  __shared__ unsigned char As[2][8192];
  __shared__ unsigned char Bs[2][8192];
  const int bid = (int)blockIdx.x;
  int s, tidx;
  if (swz) {
    const int xcd = bid & 7;
    tidx = (bid >> 3) % NTILES;
    s = (bid / (8 * NTILES)) * 8 + xcd;
  } else {
    s = bid / NTILES;
    tidx = bid - s * NTILES;
  }
  int rem = tidx, ti = 0;
  while (rem >= 8 - ti) { rem -= 8 - ti; ++ti; }
  const int tj = ti + rem;
  const bool diag = (ti == tj);

  const int t = (int)threadIdx.x;
  const int l = t & 63, w = t >> 6;
  const int wr = w >> 1, wc = w & 1;
  const int r = l & 15, g = l >> 4;

  f32x4 acc[4][4];
#pragma unroll
  for (int mi = 0; mi < 4; ++mi)
#pragma unroll
    for (int ni = 0; ni < 4; ++ni) acc[mi][ni] = (f32x4){0.f, 0.f, 0.f, 0.f};

  // staging: thread t covers LDS bytes [i*4096 + t*16, +16), i=0,1 per matrix.
  // LDS linear layout: row*64 + kbyte, row = i*64 + (t>>2).
  // Pre-swizzled GLOBAL source: fetch k-chunk (t&3)*16 ^ ((row&3)<<4) so the
  // swizzled ds_read below sees logical k. (16B-granular XOR keeps contiguity.)
  const int srow = t >> 2;
  const int skb = ((t & 3) * 16) ^ ((srow & 3) << 4);
  const unsigned char* pa0 = xt + ((size_t)(ti * 128 + srow) << 15) + skb;
  const unsigned char* pa1 = pa0 + ((size_t)64 << 15);
  const unsigned char* pb0 = xt + ((size_t)(tj * 128 + srow) << 15) + skb;
  const unsigned char* pb1 = pb0 + ((size_t)64 << 15);

#define STAGE(B, K) do { \
    gload_lds16(pa0 + (K), &As[B][t * 16]); \
    gload_lds16(pa1 + (K), &As[B][4096 + t * 16]); \
    if (!diag) { \
      gload_lds16(pb0 + (K), &Bs[B][t * 16]); \
      gload_lds16(pb1 + (K), &Bs[B][4096 + t * 16]); \
    } \
  } while (0)

  // fragment read offsets (swizzled): lane (r,g) of frag mi reads 8B at
  // row = base + mi*16 + r, kbyte = (kk*32 + g*8) ^ ((r&3)<<4)
  const int sw = (r & 3) << 4;
  const int o0 = (g * 8) ^ sw;
  const int o1 = (32 + g * 8) ^ sw;
  const int arow = (wr * 64 + r) * 64;
  const int brow = (wc * 64 + r) * 64;

#define COMPUTE(B, DS, SB, KN) do { \
    long long av[4][2], bv[4][2]; \
    const unsigned char* Ab = As[B]; \
    const unsigned char* Bb = diag ? As[B] : Bs[B]; \
    _Pragma("unroll") \
    for (int mi = 0; mi < 4; ++mi) { \
      av[mi][0] = *(const long long*)(Ab + arow + mi * 1024 + o0); \
      av[mi][1] = *(const long long*)(Ab + arow + mi * 1024 + o1); \
      bv[mi][0] = *(const long long*)(Bb + brow + mi * 1024 + o0); \
      bv[mi][1] = *(const long long*)(Bb + brow + mi * 1024 + o1); \
    } \
    if (DS) STAGE(SB, KN); \
    _Pragma("unroll") \
    for (int mi = 0; mi < 4; ++mi) \
      _Pragma("unroll") \
      for (int ni = 0; ni < 4; ++ni) { \
        acc[mi][ni] = __builtin_amdgcn_mfma_f32_16x16x32_fp8_fp8( \
            av[mi][0], bv[ni][0], acc[mi][ni], 0, 0, 0); \
        acc[mi][ni] = __builtin_amdgcn_mfma_f32_16x16x32_fp8_fp8( \
            av[mi][1], bv[ni][1], acc[mi][ni], 0, 0, 0); \
      } \
    __syncthreads(); \
  } while (0)

  // K partition: NKB64 blocks of 64 over S splits
  const int kq = NKB64 / S, kr = NKB64 - kq * S;
  const int kb0 = s * kq + (s < kr ? s : kr);
  const int nkb = kq + (s < kr ? 1 : 0);
  size_t k = (size_t)kb0 * BK;

  STAGE(0, k);
  __syncthreads();
  int it = 0;
  for (; it + 2 <= nkb; it += 2) {
    COMPUTE(0, 1, 1, k + 64);                    // read buf0, stage buf1
    COMPUTE(1, (it + 2 < nkb), 0, k + 128);      // read buf1, stage buf0
    k += 128;
  }
  if (it < nkb) COMPUTE(0, 0, 0, 0);             // odd tail, no stage

#undef STAGE
#undef COMPUTE

  // C/D layout: col = lane&15, row = (lane>>4)*4 + reg. Tile-local 128x128 write.
  float* cp = cpart + ((size_t)s * NTILES + tidx) * TILE_ELEMS;
#pragma unroll
  for (int mi = 0; mi < 4; ++mi) {
    const int rowb = wr * 64 + mi * 16 + g * 4;
#pragma unroll
    for (int ni = 0; ni < 4; ++ni) {
      const int col = wc * 64 + ni * 16 + r;
#pragma unroll
      for (int qq = 0; qq < 4; ++qq)
        cp[(size_t)(rowb + qq) * 128 + col] = acc[mi][ni][qq];
    }
  }
}

// ---------------- epi1: reduce S partials -> csum ----------------
__global__ __launch_bounds__(256) void k_epi1(const float* __restrict__ cpart,
                                              float* __restrict__ csum, int S) {
  const int g4 = ((int)blockIdx.x * 256 + (int)threadIdx.x) * 4;
  f32x4 a = (f32x4){0.f, 0.f, 0.f, 0.f};
  for (int s = 0; s < S; ++s) {
    const f32x4 v = *(const f32x4*)(cpart + (size_t)s * (NTILES * TILE_ELEMS) + g4);
    a += v;
  }
  *(f32x4*)(csum + g4) = a;
}

// ---------------- epi2: emit full grad, mirror lower, diag fixup ----------------
__global__ __launch_bounds__(256) void k_epi2(const float* __restrict__ csum,
                                              float* __restrict__ out) {
  const int idx = (int)blockIdx.x * 256 + (int)threadIdx.x;  // 0..262143
  const int i = idx >> 8;
  const int j0 = (idx & 255) * 4;
  const int ti = i >> 7, tj = j0 >> 7;
  const float sc = 0.5f / (float)M_ROWS;
  float4 o;
  if (ti <= tj) {
    const int src = ti * 8 - (ti * (ti - 1)) / 2 + tj - ti;
    const float4 v = *(const float4*)(csum + (size_t)src * TILE_ELEMS +
                                      (size_t)(i & 127) * 128 + (j0 & 127));
    o.x = v.x * sc; o.y = v.y * sc; o.z = v.z * sc; o.w = v.w * sc;
    if (i >= j0 && i < j0 + 4) {
      const float cd = (i == j0) ? v.x : (i == j0 + 1) ? v.y : (i == j0 + 2) ? v.z : v.w;
      const float dv = 0.5f * (cd / (float)M_ROWS - 1.0f);
      if (i == j0) o.x = dv; else if (i == j0 + 1) o.y = dv;
      else if (i == j0 + 2) o.z = dv; else o.w = dv;
    }
  } else {
    const int src = tj * 8 - (tj * (tj - 1)) / 2 + ti - tj;
    const int jj = j0 & 127, ii = i & 127;
    const float* base = csum + (size_t)src * TILE_ELEMS + ii;
    o.x = base[(size_t)(jj + 0) * 128] * sc;
    o.y = base[(size_t)(jj + 1) * 128] * sc;
    o.z = base[(size_t)(jj + 2) * 128] * sc;
    o.w = base[(size_t)(jj + 3) * 128] * sc;
  }
  *(float4*)(out + (size_t)i * D_DIM + j0) = o;
}

// ---------------- fin1: row stats reduce over 16 c-tiles + block partials ----------------
__global__ __launch_bounds__(256) void k_fin1(const float* __restrict__ rssp,
                                              const float* __restrict__ rs4p,
                                              float* __restrict__ scp) {
  __shared__ float sm[3][4];
  const int t = (int)threadIdx.x;
  const int m = (int)blockIdx.x * 256 + t;
  float a = 0.f, b = 0.f;
#pragma unroll
  for (int ct = 0; ct < 16; ++ct) {
    a += rssp[ct * M_ROWS + m];
    b += rs4p[ct * M_ROWS + m];
  }
  float corr = a * a - b;
#pragma unroll
  for (int off = 32; off; off >>= 1) {
    corr += __shfl_down(corr, off);
    a += __shfl_down(a, off);
    b += __shfl_down(b, off);
  }
  const int wv = t >> 6;
  if ((t & 63) == 0) { sm[0][wv] = corr; sm[1][wv] = a; sm[2][wv] = b; }
  __syncthreads();
  if (t == 0) {
    float c4 = 0.f, a4 = 0.f, b4 = 0.f;
#pragma unroll
    for (int i = 0; i < 4; ++i) { c4 += sm[0][i]; a4 += sm[1][i]; b4 += sm[2][i]; }
    scp[(int)blockIdx.x * 4 + 0] = c4;
    scp[(int)blockIdx.x * 4 + 1] = a4;
    scp[(int)blockIdx.x * 4 + 2] = b4;
  }
}

// ---------------- fin2: final scalars ----------------
__global__ __launch_bounds__(128) void k_fin2(const float* __restrict__ scp,
                                              float* __restrict__ out) {
  __shared__ float sm[3][2];
  const int t = (int)threadIdx.x;  // 0..127
  float c = scp[t * 4 + 0], a = scp[t * 4 + 1], b = scp[t * 4 + 2];
#pragma unroll
  for (int off = 32; off; off >>= 1) {
    c += __shfl_down(c, off);
    a += __shfl_down(a, off);
    b += __shfl_down(b, off);
  }
  const int wv = t >> 6;
  if ((t & 63) == 0) { sm[0][wv] = c; sm[1][wv] = a; sm[2][wv] = b; }
  __syncthreads();
  if (t == 0) {
    const double ct = (double)sm[0][0] + (double)sm[0][1];
    const double st = (double)sm[1][0] + (double)sm[1][1];
    const double qt = (double)sm[2][0] + (double)sm[2][1];
    const double N = (double)M_ROWS * (double)D_DIM;
    out[1048576] = (float)(ct / (double)M_ROWS / ((double)D_DIM * (double)D_DIM));
    out[1048577] = (float)((qt - 2.0 * st + N) / N);
  }
}

extern "C" void kernel_launch(void* const* d_in, const int* in_sizes, int n_in,
                              void* d_out, int out_size, void* d_ws, size_t ws_size,
                              hipStream_t stream) {
  (void)in_sizes; (void)n_in; (void)out_size;
  const float* x = (const float*)d_in[0];
  float* out = (float*)d_out;
  char* ws = (char*)d_ws;

  // ws layout:
  unsigned char* xt = (unsigned char*)ws;                   // 33,554,432 B (fp8)
  float* rssp = (float*)(ws + 33554432);                    //  2,097,152 B
  float* rs4p = (float*)(ws + 35651584);                    //  2,097,152 B
  float* scp  = (float*)(ws + 37748736);                    //      4,096 B
  float* csum = (float*)(ws + 37752832);                    //  2,359,296 B
  float* cpart = (float*)(ws + 40112128);                   //  S * 2,359,296 B
  const size_t base = 40112128;
  size_t avail = (ws_size > base) ? (ws_size - base) : 0;
  int S = (int)(avail / (sizeof(float) * NTILES * TILE_ELEMS));
  if (S > 24) S = 24;                 // 24 splits: 864 blocks, ~1.4MB L2 chunk/XCD
  int swz = 0;
  if (S >= 8) { S &= ~7; swz = 1; }   // multiple of 8 -> XCD-chunked decode
  if (S < 1) S = 1;

  k_pass1<<<8192, 256, 0, stream>>>(x, xt, rssp, rs4p);
  k_gemm<<<NTILES * S, 256, 0, stream>>>(xt, cpart, S, swz);
  k_epi1<<<576, 256, 0, stream>>>(cpart, csum, S);
  k_epi2<<<1024, 256, 0, stream>>>(csum, out);
  k_fin1<<<128, 256, 0, stream>>>(rssp, rs4p, scp);
  k_fin2<<<1, 128, 0, stream>>>(scp, out);
}

// Round 8
// 85.067 us; speedup vs baseline: 2.5360x; 1.1928x over previous
//
#include <hip/hip_runtime.h>
#include <hip/hip_bf16.h>
#include <stdint.h>
#include <stddef.h>

// DecorrLoss: grad = 0.5*mean_C(offdiag) + 0.5*diag(mean(x^2)-1), corr_loss, whit_loss
// x: f32 [8,4096,1024] -> [M=32768][D=1024]
//   pass1: f32 -> fp8 e4m3 (HW cvt_pk) transposed XT [D][M]; 4x4 register byte-
//          transpose via v_perm_b32; per-row sum(x^2), sum(x^4) partials
//   gemm : C = XT*XT^T via MX-scaled fp8 MFMA 16x16x128 (unit scales = plain fp8
//          at 2x rate), 36 upper-triangle 128x128 tiles, split-K S=32 (perfectly
//          balanced 8 K-blocks each), XCD-chunked, BK=128, 2-phase dbuf LDS,
//          slot^row XOR swizzle via pre-swizzled global source. bf16-packed C.
//   epi1 : unpack+reduce S bf16 partials -> csum[36][128][128] f32
//   epi2 : emit full grad (mirror lower), scale, diag fixup
//   fin1/fin2: deterministic scalar losses (f32 path, unaffected by fp8)

#define D_DIM 1024
#define M_ROWS 32768
#define BK 128
#define NKBS (M_ROWS / BK)         // 256 K-blocks of 128
#define NTILES 36                  // 8*9/2 triangle tiles
#define TILE_ELEMS 16384           // 128*128
#define CP_U32 8192                // u32 per packed tile (128*128/2)

typedef __attribute__((ext_vector_type(4))) float f32x4;
typedef __attribute__((ext_vector_type(4))) int i32x4;
typedef __attribute__((ext_vector_type(8))) int i32x8;

__device__ inline unsigned short f2bf(float f) {
  unsigned int b = __float_as_uint(f);
  return (unsigned short)((b + 0x7fffu + ((b >> 16) & 1u)) >> 16);  // RNE
}

__device__ inline void gload_lds16(const void* g, void* l) {
  __builtin_amdgcn_global_load_lds(
      (const __attribute__((address_space(1))) void*)g,
      (__attribute__((address_space(3))) void*)l,
      16, 0, 0);
}

// ---------------- pass 1: transpose + f32->fp8 (HW) + row-stat partials ----------------
// grid: 512 m-tiles x 16 c-tiles = 8192 blocks, 256 threads
// thread (q = t>>4, cg = t&15): rows m0+4q..+3, cols c0+4cg..+3
__global__ __launch_bounds__(256) void k_pass1(const float* __restrict__ x,
                                               unsigned char* __restrict__ xt,
                                               float* __restrict__ rssp,
                                               float* __restrict__ rs4p) {
  __shared__ unsigned int sh32[16 * 68];  // [m-group 0..15][64 cols + 4 pad] u32
  const int bid = blockIdx.x;
  const int m0 = (bid & 511) * 64;
  const int ct = bid >> 9;            // c-tile 0..15
  const int c0 = ct * 64;
  const int t = (int)threadIdx.x;
  const int q = t >> 4;               // m-group (4 rows)
  const int cg = t & 15;              // col group (4 cols)

  unsigned int p[4];
  float ss[4], s4[4];
#pragma unroll
  for (int mi = 0; mi < 4; ++mi) {
    const float4 v = *(const float4*)(x + (size_t)(m0 + q * 4 + mi) * D_DIM + c0 + cg * 4);
    const float q0 = v.x * v.x, q1 = v.y * v.y, q2 = v.z * v.z, q3 = v.w * v.w;
    ss[mi] = q0 + q1 + q2 + q3;
    s4[mi] = q0 * q0 + q1 * q1 + q2 * q2 + q3 * q3;
    unsigned int u = (unsigned int)__builtin_amdgcn_cvt_pk_fp8_f32(v.x, v.y, 0, false);
    p[mi] = (unsigned int)__builtin_amdgcn_cvt_pk_fp8_f32(v.z, v.w, (int)u, true);
  }
#pragma unroll
  for (int off = 8; off; off >>= 1) {
#pragma unroll
    for (int mi = 0; mi < 4; ++mi) {
      ss[mi] += __shfl_xor(ss[mi], off, 16);
      s4[mi] += __shfl_xor(s4[mi], off, 16);
    }
  }
  if (cg == 0) {
#pragma unroll
    for (int mi = 0; mi < 4; ++mi) {
      rssp[ct * M_ROWS + m0 + q * 4 + mi] = ss[mi];
      rs4p[ct * M_ROWS + m0 + q * 4 + mi] = s4[mi];
    }
  }

  // 4x4 byte transpose in registers
  const unsigned int t01l = __builtin_amdgcn_perm(p[1], p[0], 0x05010400u);
  const unsigned int t01h = __builtin_amdgcn_perm(p[1], p[0], 0x07030602u);
  const unsigned int t23l = __builtin_amdgcn_perm(p[3], p[2], 0x05010400u);
  const unsigned int t23h = __builtin_amdgcn_perm(p[3], p[2], 0x07030602u);
  uint4 w;
  w.x = __builtin_amdgcn_perm(t23l, t01l, 0x05040100u);
  w.y = __builtin_amdgcn_perm(t23l, t01l, 0x07060302u);
  w.z = __builtin_amdgcn_perm(t23h, t01h, 0x05040100u);
  w.w = __builtin_amdgcn_perm(t23h, t01h, 0x07060302u);
  *(uint4*)&sh32[q * 68 + cg * 4] = w;
  __syncthreads();

  const int c = t >> 2, mh = t & 3;
  uint4 o;
  o.x = sh32[(mh * 4 + 0) * 68 + c];
  o.y = sh32[(mh * 4 + 1) * 68 + c];
  o.z = sh32[(mh * 4 + 2) * 68 + c];
  o.w = sh32[(mh * 4 + 3) * 68 + c];
  *(uint4*)(xt + ((size_t)(c0 + c) << 15) + m0 + mh * 16) = o;
}

// ---------------- gemm: MX-fp8 (unit scale), BK=128, 2-phase dbuf, triangle ----------
// grid: S * 36 blocks, 256 threads (4 waves, 2x2 of 64x64)
__global__ __launch_bounds__(256) void k_gemm(const unsigned char* __restrict__ xt,
                                              unsigned int* __restrict__ cpart,
                                              int S, int swz) {
  __shared__ unsigned char As[2][16384];
  __shared__ unsigned char Bs[2][16384];
  const int bid = (int)blockIdx.x;
  int s, tidx;
  if (swz) {
    const int xcd = bid & 7;
    tidx = (bid >> 3) % NTILES;
    s = (bid / (8 * NTILES)) * 8 + xcd;
  } else {
    s = bid / NTILES;
    tidx = bid - s * NTILES;
  }
  int rem = tidx, ti = 0;
  while (rem >= 8 - ti) { rem -= 8 - ti; ++ti; }
  const int tj = ti + rem;
  const bool diag = (ti == tj);

  const int t = (int)threadIdx.x;
  const int l = t & 63, w = t >> 6;
  const int wr = w >> 1, wc = w & 1;
  const int r = l & 15, g = l >> 4;

  f32x4 acc[4][4];
#pragma unroll
  for (int mi = 0; mi < 4; ++mi)
#pragma unroll
    for (int ni = 0; ni < 4; ++ni) acc[mi][ni] = (f32x4){0.f, 0.f, 0.f, 0.f};

  // staging: 4 x 4KB chunks per matrix per buffer. Thread t -> LDS dest
  // [j*4096 + t*16] = row (j*32 + t>>3), slot (t&7). Pre-swizzled global
  // source slot = (t&7) ^ (row&7)  (row&7 == (t>>3)&7 since j*32 % 8 == 0).
  const int srow = t >> 3;                          // 0..31
  const int sl = (((t & 7) ^ (srow & 7)) << 4);     // swizzled 16B slot offset
  const unsigned char* pa[4];
  const unsigned char* pb[4];
#pragma unroll
  for (int j = 0; j < 4; ++j) {
    pa[j] = xt + ((size_t)(ti * 128 + j * 32 + srow) << 15) + sl;
    pb[j] = xt + ((size_t)(tj * 128 + j * 32 + srow) << 15) + sl;
  }

#define STAGE(B, K) do { \
    _Pragma("unroll") \
    for (int j = 0; j < 4; ++j) { \
      gload_lds16(pa[j] + (K), &As[B][j * 4096 + t * 16]); \
      if (!diag) gload_lds16(pb[j] + (K), &Bs[B][j * 4096 + t * 16]); \
    } \
  } while (0)

  // fragment reads: lane (r,g), frag mi: row = base + mi*16 + r (stride 128B),
  // k-chunks 2g, 2g+1 at swizzled slots (2g+h) ^ (r&7).
  const int swb = r & 7;
  const int oA0 = (((2 * g + 0) ^ swb) << 4);
  const int oA1 = (((2 * g + 1) ^ swb) << 4);
  const int arow = (wr * 64 + r) * 128;
  const int brow = (wc * 64 + r) * 128;

#define COMPUTE(B, DS, SB, KN) do { \
    i32x4 alo[4], ahi[4], blo[4], bhi[4]; \
    const unsigned char* Ab = As[B]; \
    const unsigned char* Bb = diag ? As[B] : Bs[B]; \
    _Pragma("unroll") \
    for (int mi = 0; mi < 4; ++mi) { \
      alo[mi] = *(const i32x4*)(Ab + arow + mi * 2048 + oA0); \
      ahi[mi] = *(const i32x4*)(Ab + arow + mi * 2048 + oA1); \
      blo[mi] = *(const i32x4*)(Bb + brow + mi * 2048 + oA0); \
      bhi[mi] = *(const i32x4*)(Bb + brow + mi * 2048 + oA1); \
    } \
    if (DS) STAGE(SB, KN); \
    i32x8 a8[4], b8[4]; \
    _Pragma("unroll") \
    for (int mi = 0; mi < 4; ++mi) { \
      a8[mi] = (i32x8){alo[mi][0], alo[mi][1], alo[mi][2], alo[mi][3], \
                       ahi[mi][0], ahi[mi][1], ahi[mi][2], ahi[mi][3]}; \
      b8[mi] = (i32x8){blo[mi][0], blo[mi][1], blo[mi][2], blo[mi][3], \
                       bhi[mi][0], bhi[mi][1], bhi[mi][2], bhi[mi][3]}; \
    } \
    _Pragma("unroll") \
    for (int mi = 0; mi < 4; ++mi) \
      _Pragma("unroll") \
      for (int ni = 0; ni < 4; ++ni) \
        acc[mi][ni] = __builtin_amdgcn_mfma_scale_f32_16x16x128_f8f6f4( \
            a8[mi], b8[ni], acc[mi][ni], 0, 0, 0, 0x7F7F7F7Fu, 0, 0x7F7F7F7Fu); \
    __syncthreads(); \
  } while (0)

  // K partition: NKBS blocks of BK over S splits (S=32 -> exactly 8 each)
  const int kq = NKBS / S, kr = NKBS - kq * S;
  const int kb0 = s * kq + (s < kr ? s : kr);
  const int nkb = kq + (s < kr ? 1 : 0);
  size_t k = (size_t)kb0 * BK;

  STAGE(0, k);
  __syncthreads();
  int it = 0;
  for (; it + 2 <= nkb; it += 2) {
    COMPUTE(0, 1, 1, k + BK);                     // read buf0, stage buf1
    COMPUTE(1, (it + 2 < nkb), 0, k + 2 * BK);    // read buf1, stage buf0
    k += 2 * BK;
  }
  if (it < nkb) COMPUTE(0, 0, 0, 0);              // odd tail, no stage

#undef STAGE
#undef COMPUTE

  // C/D layout: col = lane&15, row = (lane>>4)*4 + reg. Pack row-pairs as bf16.
  // cpart tile layout: u32 [64 rowpairs][128 cols].
  unsigned int* cp = cpart + ((size_t)s * NTILES + tidx) * CP_U32;
#pragma unroll
  for (int mi = 0; mi < 4; ++mi) {
    const int rowb = wr * 64 + mi * 16 + g * 4;   // even
#pragma unroll
    for (int ni = 0; ni < 4; ++ni) {
      const int col = wc * 64 + ni * 16 + r;
      const unsigned int w0 = (unsigned int)f2bf(acc[mi][ni][0]) |
                              ((unsigned int)f2bf(acc[mi][ni][1]) << 16);
      const unsigned int w1 = (unsigned int)f2bf(acc[mi][ni][2]) |
                              ((unsigned int)f2bf(acc[mi][ni][3]) << 16);
      cp[(size_t)((rowb >> 1) + 0) * 128 + col] = w0;
      cp[(size_t)((rowb >> 1) + 1) * 128 + col] = w1;
    }
  }
}

// ---------------- epi1: unpack + reduce S bf16 partials -> csum f32 ----------------
// grid 288 x 256: thread handles uint4 = (1 rowpair, 4 cols) of one tile
__global__ __launch_bounds__(256) void k_epi1(const unsigned int* __restrict__ cpart,
                                              float* __restrict__ csum, int S) {
  const int i4 = ((int)blockIdx.x * 256 + (int)threadIdx.x) * 4;  // u32 index
  float lo0 = 0.f, lo1 = 0.f, lo2 = 0.f, lo3 = 0.f;
  float hi0 = 0.f, hi1 = 0.f, hi2 = 0.f, hi3 = 0.f;
  for (int s = 0; s < S; ++s) {
    const uint4 v = *(const uint4*)(cpart + (size_t)s * (NTILES * CP_U32) + i4);
    lo0 += __uint_as_float(v.x << 16); hi0 += __uint_as_float(v.x & 0xFFFF0000u);
    lo1 += __uint_as_float(v.y << 16); hi1 += __uint_as_float(v.y & 0xFFFF0000u);
    lo2 += __uint_as_float(v.z << 16); hi2 += __uint_as_float(v.z & 0xFFFF0000u);
    lo3 += __uint_as_float(v.w << 16); hi3 += __uint_as_float(v.w & 0xFFFF0000u);
  }
  const int tile = i4 >> 13;           // / CP_U32
  const int qq = i4 & (CP_U32 - 1);
  const int rp = qq >> 7, c = qq & 127;
  float* base = csum + (size_t)tile * TILE_ELEMS + (size_t)(2 * rp) * 128 + c;
  float4 a; a.x = lo0; a.y = lo1; a.z = lo2; a.w = lo3;
  float4 b; b.x = hi0; b.y = hi1; b.z = hi2; b.w = hi3;
  *(float4*)base = a;
  *(float4*)(base + 128) = b;
}

// ---------------- epi2: emit full grad, mirror lower, diag fixup ----------------
__global__ __launch_bounds__(256) void k_epi2(const float* __restrict__ csum,
                                              float* __restrict__ out) {
  const int idx = (int)blockIdx.x * 256 + (int)threadIdx.x;  // 0..262143
  const int i = idx >> 8;
  const int j0 = (idx & 255) * 4;
  const int ti = i >> 7, tj = j0 >> 7;
  const float sc = 0.5f / (float)M_ROWS;
  float4 o;
  if (ti <= tj) {
    const int src = ti * 8 - (ti * (ti - 1)) / 2 + tj - ti;
    const float4 v = *(const float4*)(csum + (size_t)src * TILE_ELEMS +
                                      (size_t)(i & 127) * 128 + (j0 & 127));
    o.x = v.x * sc; o.y = v.y * sc; o.z = v.z * sc; o.w = v.w * sc;
    if (i >= j0 && i < j0 + 4) {
      const float cd = (i == j0) ? v.x : (i == j0 + 1) ? v.y : (i == j0 + 2) ? v.z : v.w;
      const float dv = 0.5f * (cd / (float)M_ROWS - 1.0f);
      if (i == j0) o.x = dv; else if (i == j0 + 1) o.y = dv;
      else if (i == j0 + 2) o.z = dv; else o.w = dv;
    }
  } else {
    const int src = tj * 8 - (tj * (tj - 1)) / 2 + ti - tj;
    const int jj = j0 & 127, ii = i & 127;
    const float* base = csum + (size_t)src * TILE_ELEMS + ii;
    o.x = base[(size_t)(jj + 0) * 128] * sc;
    o.y = base[(size_t)(jj + 1) * 128] * sc;
    o.z = base[(size_t)(jj + 2) * 128] * sc;
    o.w = base[(size_t)(jj + 3) * 128] * sc;
  }
  *(float4*)(out + (size_t)i * D_DIM + j0) = o;
}

// ---------------- fin1: row stats reduce over 16 c-tiles + block partials ----------------
__global__ __launch_bounds__(256) void k_fin1(const float* __restrict__ rssp,
                                              const float* __restrict__ rs4p,
                                              float* __restrict__ scp) {
  __shared__ float sm[3][4];
  const int t = (int)threadIdx.x;
  const int m = (int)blockIdx.x * 256 + t;
  float a = 0.f, b = 0.f;
#pragma unroll
  for (int ct = 0; ct < 16; ++ct) {
    a += rssp[ct * M_ROWS + m];
    b += rs4p[ct * M_ROWS + m];
  }
  float corr = a * a - b;
#pragma unroll
  for (int off = 32; off; off >>= 1) {
    corr += __shfl_down(corr, off);
    a += __shfl_down(a, off);
    b += __shfl_down(b, off);
  }
  const int wv = t >> 6;
  if ((t & 63) == 0) { sm[0][wv] = corr; sm[1][wv] = a; sm[2][wv] = b; }
  __syncthreads();
  if (t == 0) {
    float c4 = 0.f, a4 = 0.f, b4 = 0.f;
#pragma unroll
    for (int i = 0; i < 4; ++i) { c4 += sm[0][i]; a4 += sm[1][i]; b4 += sm[2][i]; }
    scp[(int)blockIdx.x * 4 + 0] = c4;
    scp[(int)blockIdx.x * 4 + 1] = a4;
    scp[(int)blockIdx.x * 4 + 2] = b4;
  }
}

// ---------------- fin2: final scalars ----------------
__global__ __launch_bounds__(128) void k_fin2(const float* __restrict__ scp,
                                              float* __restrict__ out) {
  __shared__ float sm[3][2];
  const int t = (int)threadIdx.x;  // 0..127
  float c = scp[t * 4 + 0], a = scp[t * 4 + 1], b = scp[t * 4 + 2];
#pragma unroll
  for (int off = 32; off; off >>= 1) {
    c += __shfl_down(c, off);
    a += __shfl_down(a, off);
    b += __shfl_down(b, off);
  }
  const int wv = t >> 6;
  if ((t & 63) == 0) { sm[0][wv] = c; sm[1][wv] = a; sm[2][wv] = b; }
  __syncthreads();
  if (t == 0) {
    const double ct = (double)sm[0][0] + (double)sm[0][1];
    const double st = (double)sm[1][0] + (double)sm[1][1];
    const double qt = (double)sm[2][0] + (double)sm[2][1];
    const double N = (double)M_ROWS * (double)D_DIM;
    out[1048576] = (float)(ct / (double)M_ROWS / ((double)D_DIM * (double)D_DIM));
    out[1048577] = (float)((qt - 2.0 * st + N) / N);
  }
}

extern "C" void kernel_launch(void* const* d_in, const int* in_sizes, int n_in,
                              void* d_out, int out_size, void* d_ws, size_t ws_size,
                              hipStream_t stream) {
  (void)in_sizes; (void)n_in; (void)out_size;
  const float* x = (const float*)d_in[0];
  float* out = (float*)d_out;
  char* ws = (char*)d_ws;

  // ws layout:
  unsigned char* xt = (unsigned char*)ws;                   // 33,554,432 B (fp8)
  float* rssp = (float*)(ws + 33554432);                    //  2,097,152 B
  float* rs4p = (float*)(ws + 35651584);                    //  2,097,152 B
  float* scp  = (float*)(ws + 37748736);                    //      4,096 B
  float* csum = (float*)(ws + 37752832);                    //  2,359,296 B
  unsigned int* cpart = (unsigned int*)(ws + 40112128);     //  S * 1,179,648 B
  const size_t base = 40112128;
  size_t avail = (ws_size > base) ? (ws_size - base) : 0;
  int S = (int)(avail / (sizeof(unsigned int) * NTILES * CP_U32));
  if (S > 32) S = 32;                 // 32 splits: 1152 blocks, 1MB L2 chunk/XCD,
  int swz = 0;                        // perfectly balanced 8 K-blocks per split
  if (S >= 8) { S &= ~7; swz = 1; }   // multiple of 8 -> XCD-chunked decode
  if (S < 1) S = 1;

  k_pass1<<<8192, 256, 0, stream>>>(x, xt, rssp, rs4p);
  k_gemm<<<NTILES * S, 256, 0, stream>>>(xt, cpart, S, swz);
  k_epi1<<<288, 256, 0, stream>>>(cpart, csum, S);
  k_epi2<<<1024, 256, 0, stream>>>(csum, out);
  k_fin1<<<128, 256, 0, stream>>>(rssp, rs4p, scp);
  k_fin2<<<1, 128, 0, stream>>>(scp, out);
}